// Round 6
// baseline (735.860 us; speedup 1.0000x reference)
//
#include <hip/hip_runtime.h>
#include <cstdint>
#include <cstddef>

// Problem constants: x[8192,4096]f32, Wp[4096,2048]i32(1 byte each),
// scales[4096,32]f32, group=128, out[8192,4096]f32.
#define TOKENS 8192
#define IN_F   4096
#define OUT_F  4096

typedef __bf16 bf16;
typedef bf16  bf16x8 __attribute__((ext_vector_type(8)));
typedef float f32x4  __attribute__((ext_vector_type(4)));

// ---------------- pre-pass: int4 W -> bf16 ONLY (x conversion fused into GEMM) ----------------
__global__ void prep_kernel(const int* __restrict__ wp, const float* __restrict__ sc,
                            bf16* __restrict__ wout) {
    int t  = blockIdx.x * 256 + threadIdx.x;
    int j0 = t << 2;                    // first packed byte index
    int n  = j0 >> 11;
    int g  = (j0 & 2047) >> 6;
    float s = sc[(n << 5) + g];
    int4 p = *(const int4*)(wp + j0);
    bf16x8 r;
    r[0] = (bf16)((float)((p.x & 15) - 8) * s);
    r[1] = (bf16)((float)(((p.x >> 4) & 15) - 8) * s);
    r[2] = (bf16)((float)((p.y & 15) - 8) * s);
    r[3] = (bf16)((float)(((p.y >> 4) & 15) - 8) * s);
    r[4] = (bf16)((float)((p.z & 15) - 8) * s);
    r[5] = (bf16)((float)(((p.z >> 4) & 15) - 8) * s);
    r[6] = (bf16)((float)((p.w & 15) - 8) * s);
    r[7] = (bf16)((float)(((p.w >> 4) & 15) - 8) * s);
    *(bf16x8*)(wout + ((size_t)j0 << 1)) = r;
}

// ---------------- main GEMM: 256x256 tile, BK=64, 8 waves, fused A-conversion ----------------
// r4-proven schedule (222us, 0 conflicts, 57% MfmaUtil) with A staging replaced by
// reg-staged f32->bf16 (fuses the x pre-pass; saves its 201MB of HBM traffic + time).
// B stays global_load_lds (pre-swizzled global source, linear LDS dest).
// A: lane reads 32B f32 (2x float4, coalesced: 8 lanes/row x 8 rows = 2KB/wave),
// converts, ds_write_b128 to swizzled slot (row*128 + ((lane&7)^(row&7))*16) - same
// net LDS layout as before, so fragment reads are unchanged.
//
// Per tile t (buf b, other ob), 4 phases, 1 barrier each:
//  ph0: issue ST_B1(ob,t+1)[2 GLL] + A-loads(t+1)[8 float4] | ds_read af0(8)+bq0(4) | BAR | MM(0,0)
//  ph1: ds_read bq1(4)                                      | BAR | MM(0,1)
//  ph2: ds_read af1(8)                                      | BAR | MM(1,0)
//  ph3: ST_B0(b,t+2)[2] ; vmcnt(2) ; A cvt+ds_write(4 b128 -> ob) ; lgkmcnt(0) | BAR | MM(1,1)
// vmcnt(2) at ph3 keeps only B0(t+2) in flight, forcing B1(t+1)/A(t+1)/B0(t+1) landed.
// WAR audit: every LDS write lands >=2 barriers after its region's last ds_read
// (A regions of ob last read at t-1 ph0/ph2; B0 of b last read this tile ph0, write
// issued ph3; B1 of ob last read t-1 ph1). RAW: vmcnt forcing + barrier before use.
// Tail: when t+2 doesn't exist -> vmcnt(0); when t+1 doesn't exist -> no loads/writes.

#define GLL(src, dst) __builtin_amdgcn_global_load_lds( \
    (const __attribute__((address_space(1))) void*)(src), \
    (__attribute__((address_space(3))) void*)(dst), 16, 0, 0)
#define BARX() { __builtin_amdgcn_s_barrier(); __builtin_amdgcn_sched_barrier(0); }

__global__ __launch_bounds__(512, 2)
void gemm_kernel(const float* __restrict__ X, const bf16* __restrict__ B,
                 float* __restrict__ C) {
    __shared__ char smem[131072] __attribute__((aligned(128)));

    const int tid  = threadIdx.x;
    const int lane = tid & 63;
    const int w    = tid >> 6;
    const int wr   = w >> 2, wc = w & 3;
    const int lrow = lane >> 3;             // row within an 8-row stage block
    const int lcol = lane & 7;
    const int gsw  = lcol ^ lrow;           // swizzled chunk slot (row&7 == lrow)

    // bijective XCD swizzle (512 % 8 == 0)
    const int wg = ((blockIdx.x & 7) << 6) | (blockIdx.x >> 3);
    const int mt = wg >> 4;                 // 32 M-tiles
    const int nt = wg & 15;                 // 16 N-tiles

    // ---- A (x, f32) reg-staging: rows q*64 + w*8 + lrow, chunk lcol (linear read) ----
    const float* xsrc[4];
    int awr[4];
#pragma unroll
    for (int q = 0; q < 4; ++q) {
        const int arow = q * 64 + w * 8 + lrow;
        xsrc[q] = X + (size_t)(mt * 256 + arow) * IN_F + lcol * 8;
        awr[q]  = arow * 128 + gsw * 16;    // swizzled LDS byte offset within A region
    }

    // ---- B (bf16 workspace) global_load_lds staging: pre-swizzled global source ----
    const char* Bbase = (const char*)B + (size_t)(nt * 256) * (IN_F * 2);
    const int rb = (w >> 2) * 64 + (w & 3) * 8;
    const int brow0 = rb, brow1 = rb + 128, brow2 = rb + 32, brow3 = rb + 160;
    const char* gB[4];
    gB[0] = Bbase + (size_t)(brow0 + lrow) * (IN_F * 2) + gsw * 16;
    gB[1] = Bbase + (size_t)(brow1 + lrow) * (IN_F * 2) + gsw * 16;
    gB[2] = Bbase + (size_t)(brow2 + lrow) * (IN_F * 2) + gsw * 16;
    gB[3] = Bbase + (size_t)(brow3 + lrow) * (IN_F * 2) + gsw * 16;

    char* const sm = smem;
#define ST_B0(b, kt) { GLL(gB[0] + (kt) * 128, sm + (b) * 65536 + 32768 + brow0 * 128); \
                       GLL(gB[1] + (kt) * 128, sm + (b) * 65536 + 32768 + brow1 * 128); }
#define ST_B1(b, kt) { GLL(gB[2] + (kt) * 128, sm + (b) * 65536 + 32768 + brow2 * 128); \
                       GLL(gB[3] + (kt) * 128, sm + (b) * 65536 + 32768 + brow3 * 128); }

    // A loads (for K-tile kt) into regs, and swizzled LDS writes into buf b
    float4 qa[4], qb[4];
#define LDX(kt) { _Pragma("unroll") for (int q = 0; q < 4; ++q) { \
        const float4* xp = (const float4*)(xsrc[q] + (kt) * 64); \
        qa[q] = xp[0]; qb[q] = xp[1]; } }
#define WRA(b) { _Pragma("unroll") for (int q = 0; q < 4; ++q) { \
        bf16x8 v; \
        v[0] = (bf16)qa[q].x; v[1] = (bf16)qa[q].y; v[2] = (bf16)qa[q].z; v[3] = (bf16)qa[q].w; \
        v[4] = (bf16)qb[q].x; v[5] = (bf16)qb[q].y; v[6] = (bf16)qb[q].z; v[7] = (bf16)qb[q].w; \
        *(bf16x8*)(sm + (b) * 65536 + awr[q]) = v; } }

    const int m_lane = lane & 15, quad = lane >> 4, sw = m_lane & 7;
    const bf16x8* pA0 = (const bf16x8*)sm;
    const bf16x8* pB0 = (const bf16x8*)(sm + 32768);
    const bf16x8* pA1 = (const bf16x8*)(sm + 65536);
    const bf16x8* pB1 = (const bf16x8*)(sm + 98304);

    f32x4 acc[8][4];
#pragma unroll
    for (int i = 0; i < 8; ++i)
#pragma unroll
        for (int j = 0; j < 4; ++j) acc[i][j] = (f32x4)0.0f;

    // prologue: B(t0) both halves + A(t0) loads; B0(t1); force all but B0(t1); write A(t0)
    ST_B0(0, 0); ST_B1(0, 0);
    LDX(0);
    ST_B0(1, 1);
    asm volatile("s_waitcnt vmcnt(2)" ::: "memory");
    WRA(0);
    asm volatile("s_waitcnt lgkmcnt(0)" ::: "memory");
    __builtin_amdgcn_s_barrier();

#define LDA(dst, PA, qr) \
    { _Pragma("unroll") for (int i = 0; i < 4; ++i) { \
        _Pragma("unroll") for (int kh = 0; kh < 2; ++kh) { \
            dst[i][kh] = (PA)[(wr * 128 + ((qr) * 4 + i) * 16 + m_lane) * 8 + ((kh * 4 + quad) ^ sw)]; } } }
#define LDBq(dst, PB, qc) \
    { _Pragma("unroll") for (int j = 0; j < 2; ++j) { \
        _Pragma("unroll") for (int kh = 0; kh < 2; ++kh) { \
            dst[j][kh] = (PB)[(wc * 64 + ((qc) * 2 + j) * 16 + m_lane) * 8 + ((kh * 4 + quad) ^ sw)]; } } }
#define MMq(afv, bv, qr, qc) \
    { __builtin_amdgcn_s_setprio(1); \
      _Pragma("unroll") for (int i = 0; i < 4; ++i) { \
        _Pragma("unroll") for (int j = 0; j < 2; ++j) { \
          _Pragma("unroll") for (int kh = 0; kh < 2; ++kh) { \
            acc[(qr) * 4 + i][(qc) * 2 + j] = __builtin_amdgcn_mfma_f32_16x16x32_bf16( \
                afv[i][kh], bv[j][kh], acc[(qr) * 4 + i][(qc) * 2 + j], 0, 0, 0); } } } \
      __builtin_amdgcn_s_setprio(0); }

    for (int it = 0; it < 32; ++it) {
        const int kt0 = 2 * it;
        const int kt1 = kt0 + 1;
        const bool more = (it < 31);
        {   // ---- tile kt0 from buf0 (stages target buf1 / own B0 for kt0+2) ----
            bf16x8 af0[4][2], af1[4][2], bq0[2][2], bq1[2][2];
            ST_B1(1, kt1);                     // ph0
            LDX(kt1);                          //   A loads for kt1 (always exists)
            LDA(af0, pA0, 0); LDBq(bq0, pB0, 0);
            BARX(); MMq(af0, bq0, 0, 0);
            LDBq(bq1, pB0, 1);                 // ph1
            BARX(); MMq(af0, bq1, 0, 1);
            LDA(af1, pA0, 1);                  // ph2
            BARX(); MMq(af1, bq0, 1, 0);
            if (more) {                        // ph3
                ST_B0(0, kt0 + 2);
                asm volatile("s_waitcnt vmcnt(2)" ::: "memory");
            } else {
                asm volatile("s_waitcnt vmcnt(0)" ::: "memory");
            }
            WRA(1);                            //   A(kt1) -> buf1
            asm volatile("s_waitcnt lgkmcnt(0)" ::: "memory");
            BARX(); MMq(af1, bq1, 1, 1);
        }
        {   // ---- tile kt1 from buf1 (stages target buf0 / own B0 for kt1+2) ----
            bf16x8 af0[4][2], af1[4][2], bq0[2][2], bq1[2][2];
            if (more) {                        // ph0
                ST_B1(0, kt1 + 1);
                LDX(kt1 + 1);
            }
            LDA(af0, pA1, 0); LDBq(bq0, pB1, 0);
            BARX(); MMq(af0, bq0, 0, 0);
            LDBq(bq1, pB1, 1);                 // ph1
            BARX(); MMq(af0, bq1, 0, 1);
            LDA(af1, pA1, 1);                  // ph2
            BARX(); MMq(af1, bq0, 1, 0);
            if (more) {                        // ph3
                ST_B0(1, kt1 + 2);
                asm volatile("s_waitcnt vmcnt(2)" ::: "memory");
                WRA(0);                        //   A(kt1+1) -> buf0
                asm volatile("s_waitcnt lgkmcnt(0)" ::: "memory");
            }
            BARX(); MMq(af1, bq1, 1, 1);
        }
    }

    // epilogue: C/D layout col=lane&15, row=quad*4+reg (m89-verified)
    const size_t crow0 = (size_t)(mt * 256 + wr * 128 + quad * 4) * OUT_F
                       + (size_t)(nt * 256 + wc * 64 + m_lane);
#pragma unroll
    for (int i = 0; i < 8; ++i)
#pragma unroll
        for (int r = 0; r < 4; ++r) {
            float* cp = C + crow0 + (size_t)(i * 16 + r) * OUT_F;
#pragma unroll
            for (int j = 0; j < 4; ++j) cp[j * 16] = acc[i][j][r];
        }
}

// ---------------- fallback (only if ws too small): slow but correct ----------------
__global__ void naive_kernel(const float* __restrict__ x, const int* __restrict__ wp,
                             const float* __restrict__ sc, float* __restrict__ out) {
    int o = blockIdx.x * 256 + threadIdx.x;
    int t = o >> 12, n = o & 4095;
    const float* xr = x + (size_t)t * IN_F;
    const int*   wr2 = wp + (size_t)n * (IN_F / 2);
    float acc = 0.f;
    for (int g = 0; g < 32; ++g) {
        float s = sc[n * 32 + g];
        float part = 0.f;
        for (int j = 0; j < 64; ++j) {
            int p = wr2[g * 64 + j];
            part += xr[g * 128 + 2 * j]     * (float)((p & 15) - 8);
            part += xr[g * 128 + 2 * j + 1] * (float)(((p >> 4) & 15) - 8);
        }
        acc += part * s;
    }
    out[o] = acc;
}

extern "C" void kernel_launch(void* const* d_in, const int* in_sizes, int n_in,
                              void* d_out, int out_size, void* d_ws, size_t ws_size,
                              hipStream_t stream) {
    const float* x  = (const float*)d_in[0];
    const int*   wp = (const int*)d_in[1];
    const float* sc = (const float*)d_in[2];
    float* out = (float*)d_out;

    const size_t wb_bytes = (size_t)OUT_F * IN_F * 2;    // 32 MiB

    if (ws_size >= wb_bytes) {
        bf16* wb = (bf16*)d_ws;
        prep_kernel<<<dim3(8192), dim3(256), 0, stream>>>(wp, sc, wb);
        gemm_kernel<<<dim3((TOKENS / 256) * (OUT_F / 256)), dim3(512), 0, stream>>>(x, wb, out);
    } else {
        naive_kernel<<<dim3((TOKENS * OUT_F) / 256), dim3(256), 0, stream>>>(x, wp, sc, out);
    }
}